// Round 2
// baseline (1119.696 us; speedup 1.0000x reference)
//
#include <hip/hip_runtime.h>
#include <hip/hip_bf16.h>

// Problem constants (shapes fixed by reference; N,E read from in_sizes at launch)
#define MUL 32
#define EPB 8          // edges per block-iteration in edge kernel

static __device__ __forceinline__ float silu_f(float z) {
    return z / (1.0f + __expf(-z));
}

// ---------------------------------------------------------------------------
// Kernel A: per-node pre-pass.
//   sc  = [x0@W_sc0, einsum(x1,W_sc1)] * inv * a   -> written into d_out
//   y   = [x0@W_l1_0, einsum(x1,W_l1_1)] * inv * a -> ws
// Layout of 128-wide rows: [0..32) = l0 part, [32 + u*3 + c) = l1 part.
// ---------------------------------------------------------------------------
__global__ __launch_bounds__(128) void node_pre_kernel(
    const float* __restrict__ x, const float* __restrict__ attr,
    const float* __restrict__ Wsc0, const float* __restrict__ Wsc1,
    const float* __restrict__ Wl10, const float* __restrict__ Wl11,
    float* __restrict__ sc_out, float* __restrict__ y_out, int N)
{
    __shared__ float sW[4][MUL * MUL];
    __shared__ float xs[128];
    const int tid = threadIdx.x;
    for (int i = tid; i < MUL * MUL; i += 128) {
        sW[0][i] = Wsc0[i];
        sW[1][i] = Wsc1[i];
        sW[2][i] = Wl10[i];
        sW[3][i] = Wl11[i];
    }
    __syncthreads();

    const float inv = 0.17677669529663687f; // 1/sqrt(32)
    for (int n = blockIdx.x; n < N; n += gridDim.x) {
        xs[tid] = x[(size_t)n * 128 + tid];
        __syncthreads();
        const float scale = inv * attr[n];
        if (tid < MUL) {
            float acc0 = 0.f, acc1 = 0.f;
#pragma unroll
            for (int u = 0; u < MUL; ++u) {
                const float xv = xs[u];
                acc0 += xv * sW[0][u * MUL + tid];
                acc1 += xv * sW[2][u * MUL + tid];
            }
            sc_out[(size_t)n * 128 + tid] = acc0 * scale;
            y_out [(size_t)n * 128 + tid] = acc1 * scale;
        } else {
            const int idx = tid - MUL;           // [0,96)
            const int v = idx / 3, c = idx - v * 3;
            float acc0 = 0.f, acc1 = 0.f;
#pragma unroll
            for (int u = 0; u < MUL; ++u) {
                const float xv = xs[MUL + u * 3 + c];
                acc0 += xv * sW[1][u * MUL + v];
                acc1 += xv * sW[3][u * MUL + v];
            }
            sc_out[(size_t)n * 128 + tid] = acc0 * scale;
            y_out [(size_t)n * 128 + tid] = acc1 * scale;
        }
        __syncthreads();
    }
}

// ---------------------------------------------------------------------------
// Kernel B: edge pass. Per edge: MLP 10->100(silu)->128 weights, gather y[src],
// tensor product with edge_sh, atomic scatter-add 256 floats into sums[dst].
// Thread mapping phase3: tid = e*32 + u  (8 edges x 32 channels).
// ---------------------------------------------------------------------------
__global__ __launch_bounds__(256) void edge_kernel(
    const int* __restrict__ esrc, const int* __restrict__ edst,
    const float* __restrict__ esh, const float* __restrict__ escal,
    const float* __restrict__ Wfc1, const float* __restrict__ Wfc2,
    const float* __restrict__ y,
    float* __restrict__ sums, float* __restrict__ cnt, int E)
{
    __shared__ float sW1[10 * 100];
    __shared__ float sW2[100 * 128];
    __shared__ float sS[EPB][10];
    __shared__ float sH[EPB][100];
    __shared__ float sSh[EPB][4];
    __shared__ int   sSrc[EPB];
    __shared__ int   sDst[EPB];

    const int tid = threadIdx.x;
    for (int i = tid; i < 10 * 100; i += 256) sW1[i] = Wfc1[i];
    for (int i = tid; i < 100 * 128; i += 256) sW2[i] = Wfc2[i];

    const float inv_s10 = 0.31622776601683794f; // 1/sqrt(10)
    const float inv_100 = 0.1f;                 // 1/sqrt(100)
    const float inv_s3  = 0.5773502691896258f;  // 1/sqrt(3)

    for (int base = blockIdx.x * EPB; base < E; base += gridDim.x * EPB) {
        __syncthreads();  // previous iteration done with sH/sSh/sSrc/sDst
        // ---- stage per-batch inputs ----
        if (tid < EPB * 10) {                 // edge_scalars: 80 consecutive floats
            const int e = tid / 10, k = tid - (tid / 10) * 10;
            const int ge = base + e;
            sS[e][k] = (ge < E) ? escal[(size_t)ge * 10 + k] : 0.f;
        } else if (tid >= 128 && tid < 128 + EPB * 4) {  // edge_sh
            const int i = tid - 128;
            const int e = i >> 2, k = i & 3;
            const int ge = base + e;
            sSh[e][k] = (ge < E) ? esh[(size_t)ge * 4 + k] : 0.f;
        } else if (tid >= 192 && tid < 192 + EPB) {
            const int ge = base + (tid - 192);
            sSrc[tid - 192] = (ge < E) ? esrc[ge] : 0;
        } else if (tid >= 208 && tid < 208 + EPB) {
            const int ge = base + (tid - 208);
            sDst[tid - 208] = (ge < E) ? edst[ge] : 0;
        }
        __syncthreads();

        // ---- phase 1: h = silu(scalars @ W_fc1 / sqrt(10)), 800 entries ----
        for (int idx = tid; idx < EPB * 100; idx += 256) {
            const int e = idx / 100, j = idx - e * 100;
            float acc = 0.f;
#pragma unroll
            for (int k = 0; k < 10; ++k) acc += sS[e][k] * sW1[k * 100 + j];
            acc *= inv_s10;
            sH[e][j] = silu_f(acc);
        }
        __syncthreads();

        // ---- phase 2+3: w dots, tensor product, scatter ----
        const int e = tid >> 5, u = tid & 31;
        const int ge = base + e;
        if (ge < E) {
            float w0 = 0.f, w1 = 0.f, w2 = 0.f, w3 = 0.f;
#pragma unroll 10
            for (int j = 0; j < 100; ++j) {
                const float hv = sH[e][j];
                const float* wrow = &sW2[j * 128];
                w0 += hv * wrow[u];
                w1 += hv * wrow[u + 32];
                w2 += hv * wrow[u + 64];
                w3 += hv * wrow[u + 96];
            }
            const float w00 = w0 * inv_100, w11 = w1 * inv_100;
            const float w01 = w2 * inv_100, w10 = w3 * inv_100;

            const int s = sSrc[e], d = sDst[e];
            const float* yb = y + (size_t)s * 128;
            const float y0v = yb[u];
            const float y1a = yb[MUL + u * 3 + 0];
            const float y1b = yb[MUL + u * 3 + 1];
            const float y1c = yb[MUL + u * 3 + 2];
            const float sh0 = sSh[e][0];
            const float s1 = sSh[e][1], s2 = sSh[e][2], s3 = sSh[e][3];

            float* S = sums + (size_t)d * 256;
            unsafeAtomicAdd(S + u, w00 * y0v * sh0);
            const float d11 = y1a * s1 + y1b * s2 + y1c * s3;
            unsafeAtomicAdd(S + 32 + u, w11 * d11 * inv_s3);
            unsafeAtomicAdd(S + 64 + u * 3 + 0, w01 * y0v * s1);
            unsafeAtomicAdd(S + 64 + u * 3 + 1, w01 * y0v * s2);
            unsafeAtomicAdd(S + 64 + u * 3 + 2, w01 * y0v * s3);
            unsafeAtomicAdd(S + 160 + u * 3 + 0, w10 * y1a * sh0);
            unsafeAtomicAdd(S + 160 + u * 3 + 1, w10 * y1b * sh0);
            unsafeAtomicAdd(S + 160 + u * 3 + 2, w10 * y1c * sh0);
            if (u == 0) unsafeAtomicAdd(cnt + d, 1.0f);
        }
    }
}

// ---------------------------------------------------------------------------
// Kernel C: per-node post-pass. mean = sums/max(cnt,1); alpha/conv; out += .
// ---------------------------------------------------------------------------
__global__ __launch_bounds__(128) void node_post_kernel(
    const float* __restrict__ sums, const float* __restrict__ cnt,
    const float* __restrict__ attr,
    const float* __restrict__ Wl20, const float* __restrict__ Wl21,
    const float* __restrict__ Walpha,
    float* __restrict__ out, int N)
{
    __shared__ float sW0[64 * 32];
    __shared__ float sW1[64 * 32];
    __shared__ float sWa[64];
    __shared__ float mid[256];
    const int tid = threadIdx.x;
    for (int i = tid; i < 64 * 32; i += 128) {
        sW0[i] = Wl20[i];
        sW1[i] = Wl21[i];
    }
    if (tid < 64) sWa[tid] = Walpha[tid];
    __syncthreads();

    const float inv2 = 0.125f; // 1/sqrt(64)
    for (int n = blockIdx.x; n < N; n += gridDim.x) {
        const float rinv = 1.0f / fmaxf(cnt[n], 1.0f);
        mid[tid]       = sums[(size_t)n * 256 + tid] * rinv;
        mid[tid + 128] = sums[(size_t)n * 256 + 128 + tid] * rinv;
        __syncthreads();

        const float a = attr[n];
        float alpha = 0.f;
#pragma unroll
        for (int u = 0; u < 64; ++u) alpha += mid[u] * sWa[u];
        alpha *= inv2 * a;

        float conv;
        if (tid < 32) {
            float acc = 0.f;
#pragma unroll
            for (int u = 0; u < 64; ++u) acc += mid[u] * sW0[u * 32 + tid];
            conv = acc;
        } else {
            const int idx = tid - 32;
            const int v = idx / 3, c = idx - v * 3;
            float acc = 0.f;
#pragma unroll
            for (int u = 0; u < 64; ++u) acc += mid[64 + u * 3 + c] * sW1[u * 32 + v];
            conv = acc;
        }
        conv *= inv2 * a;

        const size_t o = (size_t)n * 128 + tid;
        out[o] = out[o] + alpha * conv;
        __syncthreads();
    }
}

extern "C" void kernel_launch(void* const* d_in, const int* in_sizes, int n_in,
                              void* d_out, int out_size, void* d_ws, size_t ws_size,
                              hipStream_t stream)
{
    const float* x      = (const float*)d_in[0];
    const float* attr   = (const float*)d_in[1];
    const int*   esrc   = (const int*)  d_in[2];
    const int*   edst   = (const int*)  d_in[3];
    const float* esh    = (const float*)d_in[4];
    const float* escal  = (const float*)d_in[5];
    const float* Wfc1   = (const float*)d_in[6];
    const float* Wfc2   = (const float*)d_in[7];
    const float* Wsc0   = (const float*)d_in[8];
    const float* Wsc1   = (const float*)d_in[9];
    const float* Wl10   = (const float*)d_in[10];
    const float* Wl11   = (const float*)d_in[11];
    const float* Wl20   = (const float*)d_in[12];
    const float* Wl21   = (const float*)d_in[13];
    const float* Walpha = (const float*)d_in[14];

    const int N = in_sizes[1];   // node_attr is (N,1)
    const int E = in_sizes[2];   // edge_src is (E,)
    float* out = (float*)d_out;

    // ws layout: y (N*128) | sums (N*256) | cnt (N)
    float* y    = (float*)d_ws;
    float* sums = y + (size_t)N * 128;
    float* cnt  = sums + (size_t)N * 256;

    // zero sums + cnt (contiguous, N*257 floats)
    hipMemsetAsync(sums, 0, (size_t)N * 257 * sizeof(float), stream);

    node_pre_kernel<<<2048, 128, 0, stream>>>(x, attr, Wsc0, Wsc1, Wl10, Wl11,
                                              out, y, N);
    edge_kernel<<<2048, 256, 0, stream>>>(esrc, edst, esh, escal, Wfc1, Wfc2,
                                          y, sums, cnt, E);
    node_post_kernel<<<2048, 128, 0, stream>>>(sums, cnt, attr, Wl20, Wl21,
                                               Walpha, out, N);
}

// Round 3
// 1087.544 us; speedup vs baseline: 1.0296x; 1.0296x over previous
//
#include <hip/hip_runtime.h>
#include <hip/hip_bf16.h>

#define MUL 32
#define EPB 16          // edges per block-iteration in edge kernel

typedef _Float16 f16x8 __attribute__((ext_vector_type(8)));
typedef float f32x4 __attribute__((ext_vector_type(4)));

static __device__ __forceinline__ float silu_f(float z) {
    return z / (1.0f + __expf(-z));
}

// ---------------------------------------------------------------------------
// Kernel A: per-node pre-pass. (unchanged from r0 baseline)
//   sc  = [x0@W_sc0, einsum(x1,W_sc1)] * inv * a   -> written into d_out
//   y   = [x0@W_l1_0, einsum(x1,W_l1_1)] * inv * a -> ws
// ---------------------------------------------------------------------------
__global__ __launch_bounds__(128) void node_pre_kernel(
    const float* __restrict__ x, const float* __restrict__ attr,
    const float* __restrict__ Wsc0, const float* __restrict__ Wsc1,
    const float* __restrict__ Wl10, const float* __restrict__ Wl11,
    float* __restrict__ sc_out, float* __restrict__ y_out, int N)
{
    __shared__ float sW[4][MUL * MUL];
    __shared__ float xs[128];
    const int tid = threadIdx.x;
    for (int i = tid; i < MUL * MUL; i += 128) {
        sW[0][i] = Wsc0[i];
        sW[1][i] = Wsc1[i];
        sW[2][i] = Wl10[i];
        sW[3][i] = Wl11[i];
    }
    __syncthreads();

    const float inv = 0.17677669529663687f; // 1/sqrt(32)
    for (int n = blockIdx.x; n < N; n += gridDim.x) {
        xs[tid] = x[(size_t)n * 128 + tid];
        __syncthreads();
        const float scale = inv * attr[n];
        if (tid < MUL) {
            float acc0 = 0.f, acc1 = 0.f;
#pragma unroll
            for (int u = 0; u < MUL; ++u) {
                const float xv = xs[u];
                acc0 += xv * sW[0][u * MUL + tid];
                acc1 += xv * sW[2][u * MUL + tid];
            }
            sc_out[(size_t)n * 128 + tid] = acc0 * scale;
            y_out [(size_t)n * 128 + tid] = acc1 * scale;
        } else {
            const int idx = tid - MUL;
            const int v = idx / 3, c = idx - v * 3;
            float acc0 = 0.f, acc1 = 0.f;
#pragma unroll
            for (int u = 0; u < MUL; ++u) {
                const float xv = xs[MUL + u * 3 + c];
                acc0 += xv * sW[1][u * MUL + v];
                acc1 += xv * sW[3][u * MUL + v];
            }
            sc_out[(size_t)n * 128 + tid] = acc0 * scale;
            y_out [(size_t)n * 128 + tid] = acc1 * scale;
        }
        __syncthreads();
    }
}

// ---------------------------------------------------------------------------
// Kernel B: edge pass, MFMA version.
//  Per block-iter: 16 edges.
//   phase1: h[e][k] = silu(scalars@W1/sqrt10)*0.1  -> swizzled f16 sH[16][128]
//   phase2: w = H @ W2  via mfma_f32_16x16x32_f16 (4 waves x 32 cols) -> sWout
//   phase3: tensor product + atomic scatter (16 threads/edge, 2 u each)
//  W2 staged once per block: transposed [n][k], f16, zero-padded K->128,
//  XOR-swizzled (elem idx ^ ((row&7)<<3)) to kill ds_read_b128 bank conflicts.
// ---------------------------------------------------------------------------
__global__ __launch_bounds__(256) void edge_kernel(
    const int* __restrict__ esrc, const int* __restrict__ edst,
    const float* __restrict__ esh, const float* __restrict__ escal,
    const float* __restrict__ Wfc1, const float* __restrict__ Wfc2,
    const float* __restrict__ y,
    float* __restrict__ sums, float* __restrict__ cnt, int E)
{
    __shared__ _Float16 sW2T[128 * 128];   // [n][k] swizzled, 32 KB
    __shared__ _Float16 sH[EPB * 128];     // [e][k] swizzled, 4 KB
    __shared__ float    sW1T[100 * 12];    // [k][q] padded, 4.8 KB
    __shared__ float    sWout[EPB * 132];  // [e][n] padded, 8.4 KB
    __shared__ float    sSh[EPB][4];
    __shared__ int      sSrc[EPB];
    __shared__ int      sDst[EPB];

    const int tid = threadIdx.x;

    // ---- one-time staging ----
    // zero sW2T (pad region) and sH (pad region k>=100)
    {
        int* z2 = (int*)sW2T;
        for (int i = tid; i < 128 * 128 / 2; i += 256) z2[i] = 0;
        int* zh = (int*)sH;
        for (int i = tid; i < EPB * 128 / 2; i += 256) zh[i] = 0;
    }
    __syncthreads();
    // W1 transposed: sW1T[k*12+q] = Wfc1[q*100+k]
    for (int i = tid; i < 1000; i += 256) {
        const int q = i / 100, k = i - q * 100;
        sW1T[k * 12 + q] = Wfc1[i];
    }
    // W2 transposed + f16 + swizzle: value W2[k][n] -> sW2T[(n*128+k)^((n&7)<<3)]
    for (int i = tid; i < 100 * 128; i += 256) {
        const int k = i >> 7, n = i & 127;
        sW2T[(n * 128 + k) ^ ((n & 7) << 3)] = (_Float16)Wfc2[i];
    }

    const float inv_s10 = 0.31622776601683794f; // 1/sqrt(10)
    const float inv_s3  = 0.5773502691896258f;  // 1/sqrt(3)

    const int e16  = tid >> 4;      // 0..15  (phase1 & phase3 edge)
    const int kl   = tid & 15;      // phase1 k-lane / phase3 u0
    const int wid  = tid >> 6;      // wave 0..3
    const int l    = tid & 63;
    const int row16 = l & 15;       // MFMA A-row / D-col lane
    const int kq    = l >> 4;       // 0..3

    for (int base = blockIdx.x * EPB; base < E; base += gridDim.x * EPB) {
        __syncthreads();  // prev iter's scatter done with sH/sWout/sSh

        // ---- stage per-batch edge meta ----
        if (tid >= 160 && tid < 224) {
            const int i = tid - 160;          // 0..63
            const int e = i >> 2, kk = i & 3;
            const int ge = base + e;
            sSh[e][kk] = (ge < E) ? esh[(size_t)ge * 4 + kk] : 0.f;
        } else if (tid >= 224 && tid < 240) {
            const int ge = base + (tid - 224);
            sSrc[tid - 224] = (ge < E) ? esrc[ge] : 0;
        } else if (tid >= 240) {
            const int ge = base + (tid - 240);
            sDst[tid - 240] = (ge < E) ? edst[ge] : 0;
        }

        // ---- phase 1: h -> sH (f16, swizzled), scaled by 0.1 (1/sqrt(100)) ----
        {
            const int ge = base + e16;
            float sc[10];
            if (ge < E) {
#pragma unroll
                for (int q = 0; q < 10; ++q) sc[q] = escal[(size_t)ge * 10 + q];
            } else {
#pragma unroll
                for (int q = 0; q < 10; ++q) sc[q] = 0.f;
            }
#pragma unroll
            for (int s7 = 0; s7 < 7; ++s7) {
                const int k = kl + 16 * s7;
                if (k < 100) {
                    const float4 wA = *(const float4*)&sW1T[k * 12];
                    const float4 wB = *(const float4*)&sW1T[k * 12 + 4];
                    const float2 wC = *(const float2*)&sW1T[k * 12 + 8];
                    float acc = sc[0] * wA.x + sc[1] * wA.y + sc[2] * wA.z + sc[3] * wA.w
                              + sc[4] * wB.x + sc[5] * wB.y + sc[6] * wB.z + sc[7] * wB.w
                              + sc[8] * wC.x + sc[9] * wC.y;
                    acc *= inv_s10;
                    const float h = silu_f(acc) * 0.1f;
                    sH[(e16 * 128 + k) ^ ((e16 & 7) << 3)] = (_Float16)h;
                }
            }
        }
        __syncthreads();

        // ---- phase 2: w = H @ W2 via MFMA; wave wid -> cols [wid*32, wid*32+32) ----
        {
            f32x4 acc0 = {0.f, 0.f, 0.f, 0.f};
            f32x4 acc1 = {0.f, 0.f, 0.f, 0.f};
            const int n0 = wid * 32 + row16;
            const int n1 = n0 + 16;
#pragma unroll
            for (int kk = 0; kk < 4; ++kk) {
                const int ab = (row16 * 128 + kk * 32 + kq * 8) ^ ((row16 & 7) << 3);
                const f16x8 a = *(const f16x8*)&sH[ab];
                const int b0 = (n0 * 128 + kk * 32 + kq * 8) ^ ((n0 & 7) << 3);
                const int b1 = (n1 * 128 + kk * 32 + kq * 8) ^ ((n1 & 7) << 3);
                const f16x8 bb0 = *(const f16x8*)&sW2T[b0];
                const f16x8 bb1 = *(const f16x8*)&sW2T[b1];
                acc0 = __builtin_amdgcn_mfma_f32_16x16x32_f16(a, bb0, acc0, 0, 0, 0);
                acc1 = __builtin_amdgcn_mfma_f32_16x16x32_f16(a, bb1, acc1, 0, 0, 0);
            }
            // D layout: col = lane&15, row(edge) = (lane>>4)*4 + r
#pragma unroll
            for (int r = 0; r < 4; ++r) {
                const int er = kq * 4 + r;
                sWout[er * 132 + n0] = acc0[r];
                sWout[er * 132 + n1] = acc1[r];
            }
        }
        __syncthreads();

        // ---- phase 3: tensor product + scatter. 16 threads/edge, u = kl, kl+16 ----
        {
            const int ge = base + e16;
            if (ge < E) {
                const int s = sSrc[e16], d = sDst[e16];
                const float* yb = y + (size_t)s * 128;
                const float sh0 = sSh[e16][0];
                const float s1 = sSh[e16][1], s2 = sSh[e16][2], s3 = sSh[e16][3];
                float* S = sums + (size_t)d * 256;
                const float* W = &sWout[e16 * 132];
#pragma unroll
                for (int half = 0; half < 2; ++half) {
                    const int u = kl + 16 * half;
                    const float w00 = W[u];
                    const float w11 = W[32 + u];
                    const float w01 = W[64 + u];
                    const float w10 = W[96 + u];
                    const float y0v = yb[u];
                    const float y1a = yb[MUL + u * 3 + 0];
                    const float y1b = yb[MUL + u * 3 + 1];
                    const float y1c = yb[MUL + u * 3 + 2];
                    unsafeAtomicAdd(S + u, w00 * y0v * sh0);
                    const float d11 = y1a * s1 + y1b * s2 + y1c * s3;
                    unsafeAtomicAdd(S + 32 + u, w11 * d11 * inv_s3);
                    unsafeAtomicAdd(S + 64 + u * 3 + 0, w01 * y0v * s1);
                    unsafeAtomicAdd(S + 64 + u * 3 + 1, w01 * y0v * s2);
                    unsafeAtomicAdd(S + 64 + u * 3 + 2, w01 * y0v * s3);
                    unsafeAtomicAdd(S + 160 + u * 3 + 0, w10 * y1a * sh0);
                    unsafeAtomicAdd(S + 160 + u * 3 + 1, w10 * y1b * sh0);
                    unsafeAtomicAdd(S + 160 + u * 3 + 2, w10 * y1c * sh0);
                }
                if (kl == 0) unsafeAtomicAdd(cnt + d, 1.0f);
            }
        }
    }
}

// ---------------------------------------------------------------------------
// Kernel C: per-node post-pass. (unchanged from r0 baseline)
// ---------------------------------------------------------------------------
__global__ __launch_bounds__(128) void node_post_kernel(
    const float* __restrict__ sums, const float* __restrict__ cnt,
    const float* __restrict__ attr,
    const float* __restrict__ Wl20, const float* __restrict__ Wl21,
    const float* __restrict__ Walpha,
    float* __restrict__ out, int N)
{
    __shared__ float sW0[64 * 32];
    __shared__ float sW1[64 * 32];
    __shared__ float sWa[64];
    __shared__ float mid[256];
    const int tid = threadIdx.x;
    for (int i = tid; i < 64 * 32; i += 128) {
        sW0[i] = Wl20[i];
        sW1[i] = Wl21[i];
    }
    if (tid < 64) sWa[tid] = Walpha[tid];
    __syncthreads();

    const float inv2 = 0.125f; // 1/sqrt(64)
    for (int n = blockIdx.x; n < N; n += gridDim.x) {
        const float rinv = 1.0f / fmaxf(cnt[n], 1.0f);
        mid[tid]       = sums[(size_t)n * 256 + tid] * rinv;
        mid[tid + 128] = sums[(size_t)n * 256 + 128 + tid] * rinv;
        __syncthreads();

        const float a = attr[n];
        float alpha = 0.f;
#pragma unroll
        for (int u = 0; u < 64; ++u) alpha += mid[u] * sWa[u];
        alpha *= inv2 * a;

        float conv;
        if (tid < 32) {
            float acc = 0.f;
#pragma unroll
            for (int u = 0; u < 64; ++u) acc += mid[u] * sW0[u * 32 + tid];
            conv = acc;
        } else {
            const int idx = tid - 32;
            const int v = idx / 3, c = idx - v * 3;
            float acc = 0.f;
#pragma unroll
            for (int u = 0; u < 64; ++u) acc += mid[64 + u * 3 + c] * sW1[u * 32 + v];
            conv = acc;
        }
        conv *= inv2 * a;

        const size_t o = (size_t)n * 128 + tid;
        out[o] = out[o] + alpha * conv;
        __syncthreads();
    }
}

extern "C" void kernel_launch(void* const* d_in, const int* in_sizes, int n_in,
                              void* d_out, int out_size, void* d_ws, size_t ws_size,
                              hipStream_t stream)
{
    const float* x      = (const float*)d_in[0];
    const float* attr   = (const float*)d_in[1];
    const int*   esrc   = (const int*)  d_in[2];
    const int*   edst   = (const int*)  d_in[3];
    const float* esh    = (const float*)d_in[4];
    const float* escal  = (const float*)d_in[5];
    const float* Wfc1   = (const float*)d_in[6];
    const float* Wfc2   = (const float*)d_in[7];
    const float* Wsc0   = (const float*)d_in[8];
    const float* Wsc1   = (const float*)d_in[9];
    const float* Wl10   = (const float*)d_in[10];
    const float* Wl11   = (const float*)d_in[11];
    const float* Wl20   = (const float*)d_in[12];
    const float* Wl21   = (const float*)d_in[13];
    const float* Walpha = (const float*)d_in[14];

    const int N = in_sizes[1];   // node_attr is (N,1)
    const int E = in_sizes[2];   // edge_src is (E,)
    float* out = (float*)d_out;

    // ws layout: y (N*128) | sums (N*256) | cnt (N)
    float* y    = (float*)d_ws;
    float* sums = y + (size_t)N * 128;
    float* cnt  = sums + (size_t)N * 256;

    hipMemsetAsync(sums, 0, (size_t)N * 257 * sizeof(float), stream);

    node_pre_kernel<<<2048, 128, 0, stream>>>(x, attr, Wsc0, Wsc1, Wl10, Wl11,
                                              out, y, N);
    edge_kernel<<<2048, 256, 0, stream>>>(esrc, edst, esh, escal, Wfc1, Wfc2,
                                          y, sums, cnt, E);
    node_post_kernel<<<2048, 128, 0, stream>>>(sums, cnt, attr, Wl20, Wl21,
                                               Walpha, out, N);
}

// Round 4
// 717.184 us; speedup vs baseline: 1.5612x; 1.5164x over previous
//
#include <hip/hip_runtime.h>
#include <hip/hip_bf16.h>

#define MUL 32
#define EPB 16          // edges per block-iteration in edge_w kernel
#define GB 4            // edge staging batch in gather kernel

typedef _Float16 f16x8 __attribute__((ext_vector_type(8)));
typedef float f32x4 __attribute__((ext_vector_type(4)));

static __device__ __forceinline__ float silu_f(float z) {
    return z / (1.0f + __expf(-z));
}

// ---------------------------------------------------------------------------
// Kernel A: per-node pre-pass. (unchanged, verified r2/r3)
//   sc  -> d_out,  y -> ws
// ---------------------------------------------------------------------------
__global__ __launch_bounds__(128) void node_pre_kernel(
    const float* __restrict__ x, const float* __restrict__ attr,
    const float* __restrict__ Wsc0, const float* __restrict__ Wsc1,
    const float* __restrict__ Wl10, const float* __restrict__ Wl11,
    float* __restrict__ sc_out, float* __restrict__ y_out, int N)
{
    __shared__ float sW[4][MUL * MUL];
    __shared__ float xs[128];
    const int tid = threadIdx.x;
    for (int i = tid; i < MUL * MUL; i += 128) {
        sW[0][i] = Wsc0[i];
        sW[1][i] = Wsc1[i];
        sW[2][i] = Wl10[i];
        sW[3][i] = Wl11[i];
    }
    __syncthreads();

    const float inv = 0.17677669529663687f; // 1/sqrt(32)
    for (int n = blockIdx.x; n < N; n += gridDim.x) {
        xs[tid] = x[(size_t)n * 128 + tid];
        __syncthreads();
        const float scale = inv * attr[n];
        if (tid < MUL) {
            float acc0 = 0.f, acc1 = 0.f;
#pragma unroll
            for (int u = 0; u < MUL; ++u) {
                const float xv = xs[u];
                acc0 += xv * sW[0][u * MUL + tid];
                acc1 += xv * sW[2][u * MUL + tid];
            }
            sc_out[(size_t)n * 128 + tid] = acc0 * scale;
            y_out [(size_t)n * 128 + tid] = acc1 * scale;
        } else {
            const int idx = tid - MUL;
            const int v = idx / 3, c = idx - v * 3;
            float acc0 = 0.f, acc1 = 0.f;
#pragma unroll
            for (int u = 0; u < MUL; ++u) {
                const float xv = xs[MUL + u * 3 + c];
                acc0 += xv * sW[1][u * MUL + v];
                acc1 += xv * sW[3][u * MUL + v];
            }
            sc_out[(size_t)n * 128 + tid] = acc0 * scale;
            y_out [(size_t)n * 128 + tid] = acc1 * scale;
        }
        __syncthreads();
    }
}

// ---------------------------------------------------------------------------
// CSR build: histogram -> scan -> fill (reorders src/sh into dst-order).
// ---------------------------------------------------------------------------
__global__ void hist_kernel(const int* __restrict__ edst, int* __restrict__ deg, int E)
{
    int i = blockIdx.x * blockDim.x + threadIdx.x;
    const int stride = gridDim.x * blockDim.x;
    for (; i < E; i += stride) atomicAdd(&deg[edst[i]], 1);
}

__global__ __launch_bounds__(1024) void scan_kernel(
    const int* __restrict__ deg, int* __restrict__ row_ptr, int N, int E)
{
    __shared__ int part[1024];
    const int tid = threadIdx.x;
    const int chunk = (N + 1023) / 1024;
    const int lo = min(tid * chunk, N), hi = min(lo + chunk, N);
    int s = 0;
    for (int k = lo; k < hi; ++k) s += deg[k];
    part[tid] = s;
    __syncthreads();
    for (int off = 1; off < 1024; off <<= 1) {
        const int add = (tid >= off) ? part[tid - off] : 0;
        __syncthreads();
        part[tid] += add;
        __syncthreads();
    }
    int run = part[tid] - s;   // exclusive prefix at chunk start
    for (int k = lo; k < hi; ++k) {
        row_ptr[k] = run;
        run += deg[k];
    }
    if (hi == N) row_ptr[N] = E;
}

__global__ void fill_kernel(
    const int* __restrict__ esrc, const int* __restrict__ edst,
    const float* __restrict__ esh,
    const int* __restrict__ row_ptr, int* __restrict__ cur,
    int* __restrict__ posA, int* __restrict__ src_s, float4* __restrict__ sh_s,
    int E)
{
    int i = blockIdx.x * blockDim.x + threadIdx.x;
    const int stride = gridDim.x * blockDim.x;
    for (; i < E; i += stride) {
        const int d = edst[i];
        const int p = row_ptr[d] + atomicAdd(&cur[d], 1);
        posA[i] = p;
        src_s[p] = esrc[i];
        sh_s[p] = *(const float4*)&esh[(size_t)i * 4];
    }
}

// ---------------------------------------------------------------------------
// Kernel B: edge MLP -> w, MFMA version (phases 1-2 verified r3).
// Output: w_s[pos[e]][0..128) as f16, coalesced. NO atomics.
// ---------------------------------------------------------------------------
__global__ __launch_bounds__(256) void edge_w_kernel(
    const float* __restrict__ escal,
    const float* __restrict__ Wfc1, const float* __restrict__ Wfc2,
    const int* __restrict__ posA,
    _Float16* __restrict__ w_s, int E)
{
    __shared__ _Float16 sW2T[128 * 128];   // [n][k] swizzled, 32 KB
    __shared__ _Float16 sH[EPB * 128];     // [e][k] swizzled, 4 KB
    __shared__ float    sW1T[100 * 12];    // [k][q] padded
    __shared__ float    sWout[EPB * 132];  // [e][n] padded
    __shared__ int      sPos[EPB];

    const int tid = threadIdx.x;

    {
        int* z2 = (int*)sW2T;
        for (int i = tid; i < 128 * 128 / 2; i += 256) z2[i] = 0;
        int* zh = (int*)sH;
        for (int i = tid; i < EPB * 128 / 2; i += 256) zh[i] = 0;
    }
    __syncthreads();
    for (int i = tid; i < 1000; i += 256) {
        const int q = i / 100, k = i - q * 100;
        sW1T[k * 12 + q] = Wfc1[i];
    }
    for (int i = tid; i < 100 * 128; i += 256) {
        const int k = i >> 7, n = i & 127;
        sW2T[(n * 128 + k) ^ ((n & 7) << 3)] = (_Float16)Wfc2[i];
    }

    const float inv_s10 = 0.31622776601683794f; // 1/sqrt(10)

    const int e16  = tid >> 4;      // 0..15
    const int kl   = tid & 15;
    const int wid  = tid >> 6;      // wave 0..3
    const int l    = tid & 63;
    const int row16 = l & 15;
    const int kq    = l >> 4;

    for (int base = blockIdx.x * EPB; base < E; base += gridDim.x * EPB) {
        __syncthreads();  // prev iter done with sH/sWout/sPos

        if (tid >= 240) {
            const int ge = base + (tid - 240);
            sPos[tid - 240] = (ge < E) ? posA[ge] : -1;
        }

        // ---- phase 1: h = silu(scalars@W1/sqrt10)*0.1 -> sH (f16, swizzled) ----
        {
            const int ge = base + e16;
            float sc[10];
            if (ge < E) {
#pragma unroll
                for (int q = 0; q < 10; ++q) sc[q] = escal[(size_t)ge * 10 + q];
            } else {
#pragma unroll
                for (int q = 0; q < 10; ++q) sc[q] = 0.f;
            }
#pragma unroll
            for (int s7 = 0; s7 < 7; ++s7) {
                const int k = kl + 16 * s7;
                if (k < 100) {
                    const float4 wA = *(const float4*)&sW1T[k * 12];
                    const float4 wB = *(const float4*)&sW1T[k * 12 + 4];
                    const float2 wC = *(const float2*)&sW1T[k * 12 + 8];
                    float acc = sc[0] * wA.x + sc[1] * wA.y + sc[2] * wA.z + sc[3] * wA.w
                              + sc[4] * wB.x + sc[5] * wB.y + sc[6] * wB.z + sc[7] * wB.w
                              + sc[8] * wC.x + sc[9] * wC.y;
                    acc *= inv_s10;
                    const float h = silu_f(acc) * 0.1f;
                    sH[(e16 * 128 + k) ^ ((e16 & 7) << 3)] = (_Float16)h;
                }
            }
        }
        __syncthreads();

        // ---- phase 2: w = H @ W2 via MFMA ----
        {
            f32x4 acc0 = {0.f, 0.f, 0.f, 0.f};
            f32x4 acc1 = {0.f, 0.f, 0.f, 0.f};
            const int n0 = wid * 32 + row16;
            const int n1 = n0 + 16;
#pragma unroll
            for (int kk = 0; kk < 4; ++kk) {
                const int ab = (row16 * 128 + kk * 32 + kq * 8) ^ ((row16 & 7) << 3);
                const f16x8 a = *(const f16x8*)&sH[ab];
                const int b0 = (n0 * 128 + kk * 32 + kq * 8) ^ ((n0 & 7) << 3);
                const int b1 = (n1 * 128 + kk * 32 + kq * 8) ^ ((n1 & 7) << 3);
                const f16x8 bb0 = *(const f16x8*)&sW2T[b0];
                const f16x8 bb1 = *(const f16x8*)&sW2T[b1];
                acc0 = __builtin_amdgcn_mfma_f32_16x16x32_f16(a, bb0, acc0, 0, 0, 0);
                acc1 = __builtin_amdgcn_mfma_f32_16x16x32_f16(a, bb1, acc1, 0, 0, 0);
            }
#pragma unroll
            for (int r = 0; r < 4; ++r) {
                const int er = kq * 4 + r;
                sWout[er * 132 + n0] = acc0[r];
                sWout[er * 132 + n1] = acc1[r];
            }
        }
        __syncthreads();

        // ---- phase 3: store w row as f16, coalesced (16 threads x 16B / edge) ----
        {
            const int p = sPos[e16];
            if (p >= 0) {
                const float4 a0 = *(const float4*)&sWout[e16 * 132 + kl * 8];
                const float4 a1 = *(const float4*)&sWout[e16 * 132 + kl * 8 + 4];
                f16x8 hv;
                hv[0] = (_Float16)a0.x; hv[1] = (_Float16)a0.y;
                hv[2] = (_Float16)a0.z; hv[3] = (_Float16)a0.w;
                hv[4] = (_Float16)a1.x; hv[5] = (_Float16)a1.y;
                hv[6] = (_Float16)a1.z; hv[7] = (_Float16)a1.w;
                *(f16x8*)&w_s[(size_t)p * 128 + kl * 8] = hv;
            }
        }
    }
}

// ---------------------------------------------------------------------------
// Kernel C: gather + mean + fused post. One node at a time per block (128 thr).
// Accumulates 256 sums in registers (2/thread); no atomics, no sums buffer.
// ---------------------------------------------------------------------------
__global__ __launch_bounds__(128) void gather_post_kernel(
    const _Float16* __restrict__ w_s, const int* __restrict__ src_s,
    const float4* __restrict__ sh_s, const int* __restrict__ row_ptr,
    const float* __restrict__ y, const float* __restrict__ attr,
    const float* __restrict__ Wl20, const float* __restrict__ Wl21,
    const float* __restrict__ Walpha,
    float* __restrict__ out, int N)
{
    __shared__ float sW0[64 * 32];
    __shared__ float sW1[64 * 32];
    __shared__ float sWa[64];
    __shared__ float sWrow[GB][128];
    __shared__ float sYrow[GB][128];
    __shared__ float4 sShb[GB];
    __shared__ float mid[256];

    const int tid = threadIdx.x;
    for (int i = tid; i < 64 * 32; i += 128) {
        sW0[i] = Wl20[i];
        sW1[i] = Wl21[i];
    }
    if (tid < 64) sWa[tid] = Walpha[tid];

    const float inv_s3 = 0.5773502691896258f;

    // static per-thread output mapping
    // o1 = tid:   t<32: m00[u=t] ; 32<=t<64: m11[u=t-32] ; t>=64: m01[i=t-64]
    // o2 = tid+128: t<32: m01[i=t+64] ; t>=32: m10[i=t-32]
    const int u1 = (tid >= 64) ? (tid - 64) / 3 : 0;
    const int c1 = (tid >= 64) ? (tid - 64) - u1 * 3 : 0;
    const int i2 = (tid < 32) ? (tid + 64) : (tid - 32);
    const int u2 = i2 / 3;
    const int c2 = i2 - u2 * 3;

    for (int n = blockIdx.x; n < N; n += gridDim.x) {
        const int jlo = row_ptr[n], jhi = row_ptr[n + 1];
        float acc1 = 0.f, acc2 = 0.f;

        for (int j0 = jlo; j0 < jhi; j0 += GB) {
            const int nb = min(GB, jhi - j0);
            __syncthreads();   // prev batch / prev node's mid usage done
            for (int b = 0; b < nb; ++b) {
                const int j = j0 + b;
                sWrow[b][tid] = (float)w_s[(size_t)j * 128 + tid];
                sYrow[b][tid] = y[(size_t)src_s[j] * 128 + tid];
            }
            if (tid < nb) sShb[tid] = sh_s[j0 + tid];
            __syncthreads();
            for (int b = 0; b < nb; ++b) {
                const float4 sh = sShb[b];
                const float* wr = sWrow[b];
                const float* yr = sYrow[b];
                // o1
                if (tid < 32) {
                    acc1 += wr[tid] * yr[tid] * sh.x;
                } else if (tid < 64) {
                    const int u = tid - 32;
                    const float dot = yr[32 + 3 * u] * sh.y + yr[33 + 3 * u] * sh.z
                                    + yr[34 + 3 * u] * sh.w;
                    acc1 += wr[tid] * dot * inv_s3;
                } else {
                    const float shc = (c1 == 0) ? sh.y : ((c1 == 1) ? sh.z : sh.w);
                    acc1 += wr[64 + u1] * yr[u1] * shc;
                }
                // o2
                if (tid < 32) {
                    const float shc = (c2 == 0) ? sh.y : ((c2 == 1) ? sh.z : sh.w);
                    acc2 += wr[64 + u2] * yr[u2] * shc;
                } else {
                    acc2 += wr[96 + u2] * yr[32 + 3 * u2 + c2] * sh.x;
                }
            }
        }

        __syncthreads();
        const float rdeg = (jhi > jlo) ? 1.0f / (float)(jhi - jlo) : 0.f;
        mid[tid]       = acc1 * rdeg;
        mid[tid + 128] = acc2 * rdeg;
        __syncthreads();

        if (jhi > jlo) {
            const float a = attr[n];
            float alpha = 0.f;
#pragma unroll
            for (int u = 0; u < 64; ++u) alpha += mid[u] * sWa[u];
            alpha *= 0.125f * a;

            float conv;
            if (tid < 32) {
                float acc = 0.f;
#pragma unroll
                for (int u = 0; u < 64; ++u) acc += mid[u] * sW0[u * 32 + tid];
                conv = acc;
            } else {
                const int idx = tid - 32;
                const int v = idx / 3, c = idx - v * 3;
                float acc = 0.f;
#pragma unroll
                for (int u = 0; u < 64; ++u) acc += mid[64 + u * 3 + c] * sW1[u * 32 + v];
                conv = acc;
            }
            conv *= 0.125f * a;

            const size_t o = (size_t)n * 128 + tid;
            out[o] = out[o] + alpha * conv;
        }
    }
}

extern "C" void kernel_launch(void* const* d_in, const int* in_sizes, int n_in,
                              void* d_out, int out_size, void* d_ws, size_t ws_size,
                              hipStream_t stream)
{
    const float* x      = (const float*)d_in[0];
    const float* attr   = (const float*)d_in[1];
    const int*   esrc   = (const int*)  d_in[2];
    const int*   edst   = (const int*)  d_in[3];
    const float* esh    = (const float*)d_in[4];
    const float* escal  = (const float*)d_in[5];
    const float* Wfc1   = (const float*)d_in[6];
    const float* Wfc2   = (const float*)d_in[7];
    const float* Wsc0   = (const float*)d_in[8];
    const float* Wsc1   = (const float*)d_in[9];
    const float* Wl10   = (const float*)d_in[10];
    const float* Wl11   = (const float*)d_in[11];
    const float* Wl20   = (const float*)d_in[12];
    const float* Wl21   = (const float*)d_in[13];
    const float* Walpha = (const float*)d_in[14];

    const int N = in_sizes[1];
    const int E = in_sizes[2];
    float* out = (float*)d_out;

    // ws layout: y | row_ptr | deg | cur | posA | src_s | [align16] sh_s | w_s
    char* p = (char*)d_ws;
    float* y      = (float*)p;  p += (size_t)N * 128 * sizeof(float);
    int* row_ptr  = (int*)p;    p += (size_t)(N + 1) * sizeof(int);
    int* deg      = (int*)p;    p += (size_t)N * sizeof(int);
    int* cur      = (int*)p;    p += (size_t)N * sizeof(int);
    int* posA     = (int*)p;    p += (size_t)E * sizeof(int);
    int* src_s    = (int*)p;    p += (size_t)E * sizeof(int);
    p = (char*)(((uintptr_t)p + 15) & ~(uintptr_t)15);
    float4* sh_s  = (float4*)p; p += (size_t)E * sizeof(float4);
    _Float16* w_s = (_Float16*)p;

    // zero deg + cur (contiguous)
    hipMemsetAsync(deg, 0, (size_t)2 * N * sizeof(int), stream);

    node_pre_kernel<<<2048, 128, 0, stream>>>(x, attr, Wsc0, Wsc1, Wl10, Wl11,
                                              out, y, N);
    hist_kernel<<<512, 256, 0, stream>>>(edst, deg, E);
    scan_kernel<<<1, 1024, 0, stream>>>(deg, row_ptr, N, E);
    fill_kernel<<<512, 256, 0, stream>>>(esrc, edst, esh, row_ptr, cur,
                                         posA, src_s, sh_s, E);
    edge_w_kernel<<<2048, 256, 0, stream>>>(escal, Wfc1, Wfc2, posA, w_s, E);
    gather_post_kernel<<<4096, 128, 0, stream>>>(w_s, src_s, sh_s, row_ptr,
                                                 y, attr, Wl20, Wl21, Walpha,
                                                 out, N);
}

// Round 5
// 354.214 us; speedup vs baseline: 3.1611x; 2.0247x over previous
//
#include <hip/hip_runtime.h>
#include <hip/hip_bf16.h>

#define MUL 32
#define EPB 32          // edges per block-iteration in edge_w kernel

typedef _Float16 f16x8 __attribute__((ext_vector_type(8)));
typedef float f32x4 __attribute__((ext_vector_type(4)));

static __device__ __forceinline__ float silu_f(float z) {
    return z / (1.0f + __expf(-z));
}

// ---------------------------------------------------------------------------
// Kernel A: per-node pre-pass. (unchanged, verified r2-r4)
// ---------------------------------------------------------------------------
__global__ __launch_bounds__(128) void node_pre_kernel(
    const float* __restrict__ x, const float* __restrict__ attr,
    const float* __restrict__ Wsc0, const float* __restrict__ Wsc1,
    const float* __restrict__ Wl10, const float* __restrict__ Wl11,
    float* __restrict__ sc_out, float* __restrict__ y_out, int N)
{
    __shared__ float sW[4][MUL * MUL];
    __shared__ float xs[128];
    const int tid = threadIdx.x;
    for (int i = tid; i < MUL * MUL; i += 128) {
        sW[0][i] = Wsc0[i];
        sW[1][i] = Wsc1[i];
        sW[2][i] = Wl10[i];
        sW[3][i] = Wl11[i];
    }
    __syncthreads();

    const float inv = 0.17677669529663687f; // 1/sqrt(32)
    for (int n = blockIdx.x; n < N; n += gridDim.x) {
        xs[tid] = x[(size_t)n * 128 + tid];
        __syncthreads();
        const float scale = inv * attr[n];
        if (tid < MUL) {
            float acc0 = 0.f, acc1 = 0.f;
#pragma unroll
            for (int u = 0; u < MUL; ++u) {
                const float xv = xs[u];
                acc0 += xv * sW[0][u * MUL + tid];
                acc1 += xv * sW[2][u * MUL + tid];
            }
            sc_out[(size_t)n * 128 + tid] = acc0 * scale;
            y_out [(size_t)n * 128 + tid] = acc1 * scale;
        } else {
            const int idx = tid - MUL;
            const int v = idx / 3, c = idx - v * 3;
            float acc0 = 0.f, acc1 = 0.f;
#pragma unroll
            for (int u = 0; u < MUL; ++u) {
                const float xv = xs[MUL + u * 3 + c];
                acc0 += xv * sW[1][u * MUL + v];
                acc1 += xv * sW[3][u * MUL + v];
            }
            sc_out[(size_t)n * 128 + tid] = acc0 * scale;
            y_out [(size_t)n * 128 + tid] = acc1 * scale;
        }
        __syncthreads();
    }
}

// ---------------------------------------------------------------------------
// CSR build: histogram -> scan -> fill. (unchanged, verified r4)
// ---------------------------------------------------------------------------
__global__ void hist_kernel(const int* __restrict__ edst, int* __restrict__ deg, int E)
{
    int i = blockIdx.x * blockDim.x + threadIdx.x;
    const int stride = gridDim.x * blockDim.x;
    for (; i < E; i += stride) atomicAdd(&deg[edst[i]], 1);
}

__global__ __launch_bounds__(1024) void scan_kernel(
    const int* __restrict__ deg, int* __restrict__ row_ptr, int N, int E)
{
    __shared__ int part[1024];
    const int tid = threadIdx.x;
    const int chunk = (N + 1023) / 1024;
    const int lo = min(tid * chunk, N), hi = min(lo + chunk, N);
    int s = 0;
    for (int k = lo; k < hi; ++k) s += deg[k];
    part[tid] = s;
    __syncthreads();
    for (int off = 1; off < 1024; off <<= 1) {
        const int add = (tid >= off) ? part[tid - off] : 0;
        __syncthreads();
        part[tid] += add;
        __syncthreads();
    }
    int run = part[tid] - s;
    for (int k = lo; k < hi; ++k) {
        row_ptr[k] = run;
        run += deg[k];
    }
    if (hi == N) row_ptr[N] = E;
}

__global__ void fill_kernel(
    const int* __restrict__ esrc, const int* __restrict__ edst,
    const float* __restrict__ esh,
    const int* __restrict__ row_ptr, int* __restrict__ cur,
    int* __restrict__ posA, int* __restrict__ src_s, float4* __restrict__ sh_s,
    int E)
{
    int i = blockIdx.x * blockDim.x + threadIdx.x;
    const int stride = gridDim.x * blockDim.x;
    for (; i < E; i += stride) {
        const int d = edst[i];
        const int p = row_ptr[d] + atomicAdd(&cur[d], 1);
        posA[i] = p;
        src_s[p] = esrc[i];
        sh_s[p] = *(const float4*)&esh[(size_t)i * 4];
    }
}

// ---------------------------------------------------------------------------
// Kernel B: edge MLP -> w (f16, CSR order). EPB=32, 2 barriers/iter,
// phase2 MFMA stores straight to global (no sWout round-trip).
// ---------------------------------------------------------------------------
__global__ __launch_bounds__(256) void edge_w_kernel(
    const float* __restrict__ escal,
    const float* __restrict__ Wfc1, const float* __restrict__ Wfc2,
    const int* __restrict__ posA,
    _Float16* __restrict__ w_s, int E)
{
    __shared__ _Float16 sW2T[128 * 128];   // [n][k] swizzled, 32 KB
    __shared__ _Float16 sH[EPB * 128];     // [e][k] swizzled, 8 KB
    __shared__ float    sW1T[100 * 12];    // [k][q] padded
    __shared__ int      sPos[EPB];

    const int tid = threadIdx.x;

    {
        int* z2 = (int*)sW2T;
        for (int i = tid; i < 128 * 128 / 2; i += 256) z2[i] = 0;
        int* zh = (int*)sH;
        for (int i = tid; i < EPB * 128 / 2; i += 256) zh[i] = 0;
    }
    __syncthreads();
    for (int i = tid; i < 1000; i += 256) {
        const int q = i / 100, k = i - q * 100;
        sW1T[k * 12 + q] = Wfc1[i];
    }
    for (int i = tid; i < 100 * 128; i += 256) {
        const int k = i >> 7, n = i & 127;
        sW2T[(n * 128 + k) ^ ((n & 7) << 3)] = (_Float16)Wfc2[i];
    }

    const float inv_s10 = 0.31622776601683794f; // 1/sqrt(10)

    const int e8  = tid >> 3;       // 0..31 (phase1 edge)
    const int kl8 = tid & 7;
    const int wid = tid >> 6;       // wave 0..3
    const int l   = tid & 63;
    const int row16 = l & 15;
    const int kq    = l >> 4;

    for (int base = blockIdx.x * EPB; base < E; base += gridDim.x * EPB) {
        __syncthreads();  // prev iter done reading sH/sPos

        if (tid < EPB) {
            const int ge = base + tid;
            sPos[tid] = (ge < E) ? posA[ge] : -1;
        }

        // ---- phase 1: h = silu(scalars@W1/sqrt10)*0.1 -> sH (f16, swizzled) ----
        {
            const int ge = base + e8;
            float sc[10];
            if (ge < E) {
#pragma unroll
                for (int q = 0; q < 10; ++q) sc[q] = escal[(size_t)ge * 10 + q];
            } else {
#pragma unroll
                for (int q = 0; q < 10; ++q) sc[q] = 0.f;
            }
#pragma unroll
            for (int s13 = 0; s13 < 13; ++s13) {
                const int k = kl8 + 8 * s13;
                if (k < 100) {
                    const float4 wA = *(const float4*)&sW1T[k * 12];
                    const float4 wB = *(const float4*)&sW1T[k * 12 + 4];
                    const float2 wC = *(const float2*)&sW1T[k * 12 + 8];
                    float acc = sc[0] * wA.x + sc[1] * wA.y + sc[2] * wA.z + sc[3] * wA.w
                              + sc[4] * wB.x + sc[5] * wB.y + sc[6] * wB.z + sc[7] * wB.w
                              + sc[8] * wC.x + sc[9] * wC.y;
                    acc *= inv_s10;
                    const float h = silu_f(acc) * 0.1f;
                    sH[(e8 * 128 + k) ^ ((e8 & 7) << 3)] = (_Float16)h;
                }
            }
        }
        __syncthreads();

        // ---- phase 2: w = H @ W2 via MFMA; 2 row-blocks, direct f16 store ----
        {
            f32x4 acc00 = {0.f,0.f,0.f,0.f}, acc01 = {0.f,0.f,0.f,0.f};
            f32x4 acc10 = {0.f,0.f,0.f,0.f}, acc11 = {0.f,0.f,0.f,0.f};
            const int n0 = wid * 32 + row16;
            const int n1 = n0 + 16;
#pragma unroll
            for (int kk = 0; kk < 4; ++kk) {
                const int bi0 = (n0 * 128 + kk * 32 + kq * 8) ^ ((n0 & 7) << 3);
                const int bi1 = (n1 * 128 + kk * 32 + kq * 8) ^ ((n1 & 7) << 3);
                const f16x8 bb0 = *(const f16x8*)&sW2T[bi0];
                const f16x8 bb1 = *(const f16x8*)&sW2T[bi1];
                const int ai0 = (row16 * 128 + kk * 32 + kq * 8) ^ ((row16 & 7) << 3);
                const int ai1 = ((16 + row16) * 128 + kk * 32 + kq * 8) ^ ((row16 & 7) << 3);
                const f16x8 a0 = *(const f16x8*)&sH[ai0];
                const f16x8 a1 = *(const f16x8*)&sH[ai1];
                acc00 = __builtin_amdgcn_mfma_f32_16x16x32_f16(a0, bb0, acc00, 0, 0, 0);
                acc01 = __builtin_amdgcn_mfma_f32_16x16x32_f16(a0, bb1, acc01, 0, 0, 0);
                acc10 = __builtin_amdgcn_mfma_f32_16x16x32_f16(a1, bb0, acc10, 0, 0, 0);
                acc11 = __builtin_amdgcn_mfma_f32_16x16x32_f16(a1, bb1, acc11, 0, 0, 0);
            }
            // D layout: col(n) = lane&15 -> n0/n1; row(edge) = kq*4 + r
#pragma unroll
            for (int r = 0; r < 4; ++r) {
                const int er0 = kq * 4 + r;
                const int er1 = 16 + er0;
                const int p0 = sPos[er0];
                const int p1 = sPos[er1];
                if (p0 >= 0) {
                    w_s[(size_t)p0 * 128 + n0] = (_Float16)acc00[r];
                    w_s[(size_t)p0 * 128 + n1] = (_Float16)acc01[r];
                }
                if (p1 >= 0) {
                    w_s[(size_t)p1 * 128 + n0] = (_Float16)acc10[r];
                    w_s[(size_t)p1 * 128 + n1] = (_Float16)acc11[r];
                }
            }
        }
    }
}

// ---------------------------------------------------------------------------
// Kernel C: gather + mean + fused post. ONE WAVE PER NODE, no block barriers.
// Per edge: 5 coalesced global loads, branch-free per-lane tensor product.
//   lane<32 (u=L):  m00[u] (accA) + m01[u][0..2] (acc1..3)
//   lane>=32 (u=L-32): m11[u] (accA) + m10[u][0..2] (acc1..3)
// Epilogue: alpha via shfl reduce; conv via per-wave LDS mid (mid1 transposed
// so both conv patterns read stride-1 float4).
// ---------------------------------------------------------------------------
__global__ __launch_bounds__(256) void gather_post_kernel(
    const _Float16* __restrict__ w_s, const int* __restrict__ src_s,
    const float4* __restrict__ sh_s, const int* __restrict__ row_ptr,
    const float* __restrict__ y, const float* __restrict__ attr,
    const float* __restrict__ Wl20, const float* __restrict__ Wl21,
    const float* __restrict__ Walpha,
    float* __restrict__ out, int N)
{
    __shared__ float sW0[64 * 32];
    __shared__ float sW1[64 * 32];
    __shared__ float sWa[64];
    __shared__ float sMid[4][256];   // per-wave: [mid0(64) | midT(3x64)]

    const int tid = threadIdx.x;
    for (int i = tid; i < 64 * 32; i += 256) {
        sW0[i] = Wl20[i];
        sW1[i] = Wl21[i];
    }
    if (tid < 64) sWa[tid] = Walpha[tid];
    __syncthreads();   // only barrier; node loop is barrier-free

    const int wid = tid >> 6;
    const int L   = tid & 63;
    const bool hi = (L >= 32);
    const int u   = L & 31;

    // edge-phase per-lane constants
    const int wAi = hi ? 32 + u : u;
    const int wBi = hi ? 96 + u : 64 + u;
    const int yi0 = hi ? 32 + 3 * u + 0 : u;
    const int yi1 = hi ? 32 + 3 * u + 1 : u;
    const int yi2 = hi ? 32 + 3 * u + 2 : u;
    const float mulA = hi ? 0.5773502691896258f : 1.0f;   // 1/sqrt(3) on m11

    // conv per-lane constants
    const int o1m = L - 32;                 // valid when L>=32
    const int v1 = hi ? o1m / 3 : 0;
    const int c1 = hi ? o1m - v1 * 3 : 0;
    const int o2m = L + 32;                 // o2 = L+64 -> pattern idx o2-32
    const int v2 = o2m / 3;
    const int c2 = o2m - v2 * 3;
    const float* wcol1 = hi ? (sW1 + v1) : (sW0 + L);
    const float* wcol2 = sW1 + v2;

    float* midw = &sMid[wid][0];
    const float* msrc1c = hi ? (midw + 64 + c1 * 64) : midw;
    const float* msrc2c = midw + 64 + c2 * 64;

#define ACC_EDGE(sh, wAv, wBv, q0, q1, q2) do {                        \
        const float sA0 = hi ? (sh).y : (sh).x;                        \
        const float sA1 = hi ? (sh).z : 0.f;                           \
        const float sA2 = hi ? (sh).w : 0.f;                           \
        const float b1s = hi ? (sh).x : (sh).y;                        \
        const float b2s = hi ? (sh).x : (sh).z;                        \
        const float b3s = hi ? (sh).x : (sh).w;                        \
        accA += (wAv) * mulA * ((q0) * sA0 + (q1) * sA1 + (q2) * sA2); \
        acc1 += (wBv) * (q0) * b1s;                                    \
        acc2 += (wBv) * (q1) * b2s;                                    \
        acc3 += (wBv) * (q2) * b3s;                                    \
    } while (0)

    const int waves_glob = gridDim.x * 4;
    for (int n = blockIdx.x * 4 + wid; n < N; n += waves_glob) {
        const int jlo = row_ptr[n];
        const int jhi = row_ptr[n + 1];
        const int deg = jhi - jlo;
        if (deg <= 0) continue;   // mean=0 -> alpha=0 -> out stays sc

        float accA = 0.f, acc1 = 0.f, acc2 = 0.f, acc3 = 0.f;

        int j = jlo;
        for (; j + 2 <= jhi; j += 2) {
            const int sa = src_s[j];
            const int sb = src_s[j + 1];
            const float4 shA = sh_s[j];
            const float4 shB = sh_s[j + 1];
            const _Float16* wra = w_s + (size_t)j * 128;
            const _Float16* wrb = wra + 128;
            const float* yra = y + (size_t)sa * 128;
            const float* yrb = y + (size_t)sb * 128;
            const float wAa = (float)wra[wAi], wBa = (float)wra[wBi];
            const float qa0 = yra[yi0], qa1 = yra[yi1], qa2 = yra[yi2];
            const float wAb = (float)wrb[wAi], wBb = (float)wrb[wBi];
            const float qb0 = yrb[yi0], qb1 = yrb[yi1], qb2 = yrb[yi2];
            ACC_EDGE(shA, wAa, wBa, qa0, qa1, qa2);
            ACC_EDGE(shB, wAb, wBb, qb0, qb1, qb2);
        }
        if (j < jhi) {
            const int sa = src_s[j];
            const float4 shA = sh_s[j];
            const _Float16* wra = w_s + (size_t)j * 128;
            const float* yra = y + (size_t)sa * 128;
            const float wAa = (float)wra[wAi], wBa = (float)wra[wBi];
            const float qa0 = yra[yi0], qa1 = yra[yi1], qa2 = yra[yi2];
            ACC_EDGE(shA, wAa, wBa, qa0, qa1, qa2);
        }

        const float rdeg = 1.0f / (float)deg;
        const float a = attr[n];

        // alpha = (mid0 . Wa) * inv2 * a ; mid0[L] = accA*rdeg
        float term = accA * rdeg * sWa[L];
#pragma unroll
        for (int off = 32; off; off >>= 1) term += __shfl_xor(term, off);
        const float alpha = term * 0.125f * a;

        // write mid (wave-private LDS; wave-coherent, no barrier)
        midw[L]            = accA * rdeg;
        midw[64 + L]       = acc1 * rdeg;   // midT[0][L]
        midw[128 + L]      = acc2 * rdeg;   // midT[1][L]
        midw[192 + L]      = acc3 * rdeg;   // midT[2][L]

        float cv1 = 0.f, cv2 = 0.f;
#pragma unroll
        for (int kk = 0; kk < 16; ++kk) {
            const float4 m1 = *(const float4*)&msrc1c[4 * kk];
            const float4 m2 = *(const float4*)&msrc2c[4 * kk];
            cv1 += m1.x * wcol1[(4 * kk + 0) * 32] + m1.y * wcol1[(4 * kk + 1) * 32]
                 + m1.z * wcol1[(4 * kk + 2) * 32] + m1.w * wcol1[(4 * kk + 3) * 32];
            cv2 += m2.x * wcol2[(4 * kk + 0) * 32] + m2.y * wcol2[(4 * kk + 1) * 32]
                 + m2.z * wcol2[(4 * kk + 2) * 32] + m2.w * wcol2[(4 * kk + 3) * 32];
        }
        const float f = alpha * 0.125f * a;
        const size_t ob = (size_t)n * 128;
        out[ob + L]      += f * cv1;
        out[ob + 64 + L] += f * cv2;
    }
#undef ACC_EDGE
}

extern "C" void kernel_launch(void* const* d_in, const int* in_sizes, int n_in,
                              void* d_out, int out_size, void* d_ws, size_t ws_size,
                              hipStream_t stream)
{
    const float* x      = (const float*)d_in[0];
    const float* attr   = (const float*)d_in[1];
    const int*   esrc   = (const int*)  d_in[2];
    const int*   edst   = (const int*)  d_in[3];
    const float* esh    = (const float*)d_in[4];
    const float* escal  = (const float*)d_in[5];
    const float* Wfc1   = (const float*)d_in[6];
    const float* Wfc2   = (const float*)d_in[7];
    const float* Wsc0   = (const float*)d_in[8];
    const float* Wsc1   = (const float*)d_in[9];
    const float* Wl10   = (const float*)d_in[10];
    const float* Wl11   = (const float*)d_in[11];
    const float* Wl20   = (const float*)d_in[12];
    const float* Wl21   = (const float*)d_in[13];
    const float* Walpha = (const float*)d_in[14];

    const int N = in_sizes[1];
    const int E = in_sizes[2];
    float* out = (float*)d_out;

    // ws layout: y | row_ptr | deg | cur | posA | src_s | [align16] sh_s | w_s
    char* p = (char*)d_ws;
    float* y      = (float*)p;  p += (size_t)N * 128 * sizeof(float);
    int* row_ptr  = (int*)p;    p += (size_t)(N + 1) * sizeof(int);
    int* deg      = (int*)p;    p += (size_t)N * sizeof(int);
    int* cur      = (int*)p;    p += (size_t)N * sizeof(int);
    int* posA     = (int*)p;    p += (size_t)E * sizeof(int);
    int* src_s    = (int*)p;    p += (size_t)E * sizeof(int);
    p = (char*)(((uintptr_t)p + 15) & ~(uintptr_t)15);
    float4* sh_s  = (float4*)p; p += (size_t)E * sizeof(float4);
    _Float16* w_s = (_Float16*)p;

    hipMemsetAsync(deg, 0, (size_t)2 * N * sizeof(int), stream);

    node_pre_kernel<<<2048, 128, 0, stream>>>(x, attr, Wsc0, Wsc1, Wl10, Wl11,
                                              out, y, N);
    hist_kernel<<<512, 256, 0, stream>>>(edst, deg, E);
    scan_kernel<<<1, 1024, 0, stream>>>(deg, row_ptr, N, E);
    fill_kernel<<<512, 256, 0, stream>>>(esrc, edst, esh, row_ptr, cur,
                                         posA, src_s, sh_s, E);
    edge_w_kernel<<<2048, 256, 0, stream>>>(escal, Wfc1, Wfc2, posA, w_s, E);
    gather_post_kernel<<<4096, 256, 0, stream>>>(w_s, src_s, sh_s, row_ptr,
                                                 y, attr, Wl20, Wl21, Walpha,
                                                 out, N);
}